// Round 7
// baseline (265.457 us; speedup 1.0000x reference)
//
#include <hip/hip_runtime.h>
#include <hip/hip_bf16.h>
#include <cstddef>
#include <cstdint>

// SelfAttn (SAGAN) — Round 12: register-resident flash fattn. One wave per
// block (64 thr), 32q x 128v per wave. Swapped QK^T (S^T: lane-local q) ->
// online softmax in-register (2 shfl_xor reduces) -> bf16 pack + 12-shuffle
// cross-quad marshal into PV A-frags -> PV with G direct from L2. Zero LDS,
// zero barriers. K 1-chunk register prefetch; G issued early per half-chunk.

typedef __attribute__((ext_vector_type(8))) short short8;
typedef __attribute__((ext_vector_type(4))) float float4v;
typedef __attribute__((ext_vector_type(4))) uint32_t uint4v;

namespace {
constexpr int kB = 8, kC = 512, kCK = 64, kCV = 256, kHW = 4096, kP = 1024;
constexpr int kNP = 384;  // packed projection width [theta|phi|g]
}

__device__ __forceinline__ void gll16(const void* g, void* l) {
  __builtin_amdgcn_global_load_lds((uint32_t __attribute__((address_space(1)))*)g,
                                   (uint32_t __attribute__((address_space(3)))*)l,
                                   16, 0, 0);
}
__device__ __forceinline__ float4v mfma16(short8 a, short8 b, float4v c) {
  return __builtin_amdgcn_mfma_f32_16x16x32_bf16(a, b, c, 0, 0, 0);
}
// bf16 tile row = 128B (8 octs of 16B), slot swizzle oct ^ (row&7)
__device__ __forceinline__ const short8* fragp(const char* tile, int row, int oct) {
  return (const short8*)(tile + row * 128 + ((oct ^ (row & 7)) * 16));
}
__device__ __forceinline__ uint32_t packbf(float a, float b) {
  const uint32_t lo = (uint32_t)__builtin_bit_cast(unsigned short, __float2bfloat16(a));
  const uint32_t hi = (uint32_t)__builtin_bit_cast(unsigned short, __float2bfloat16(b));
  return lo | (hi << 16);
}
__device__ __forceinline__ uint32_t sx16(uint32_t v) {
  return (uint32_t)__shfl_xor((int)v, 16);
}
__device__ __forceinline__ uint32_t sx32(uint32_t v) {
  return (uint32_t)__shfl_xor((int)v, 32);
}

// pack weights: wAll[384][512] = [theta|phi|g]^T; woT[512][256]
__global__ __launch_bounds__(256) void k_pack_w(
    const float* __restrict__ wt, const float* __restrict__ wphi,
    const float* __restrict__ wg, const float* __restrict__ wo,
    __hip_bfloat16* __restrict__ wAll, __hip_bfloat16* __restrict__ woT) {
  int idx = blockIdx.x * 256 + threadIdx.x;  // 327680
  if (idx < 196608) {
    int n = idx >> 9, k = idx & 511;
    float v = (n < 64) ? wt[k * 64 + n]
            : (n < 128) ? wphi[k * 64 + (n - 64)]
                        : wg[k * 256 + (n - 128)];
    wAll[idx] = __float2bfloat16(v);
  } else {
    int t = idx - 196608;
    int n = t >> 8, k = t & 255;
    woT[t] = __float2bfloat16(wo[k * 512 + n]);
  }
}

// ---- proj: pgf[32768][384] = bf16(x) @ wAll^T, A fp32 read direct, tile 64x384 ----
__global__ __launch_bounds__(256) void k_proj(const float* __restrict__ x,
                                              const __hip_bfloat16* __restrict__ wAll,
                                              __hip_bfloat16* __restrict__ pgf) {
  __shared__ __align__(16) char smem[16384 + 49152];
  char* As = smem;           // fp32 [64 rows][16 sq of 16B], swizzle sq^(row&15)
  char* Bs = smem + 16384;   // bf16 [384 rows][8 oct], swizzle oct^(row&7)
  const int tid = threadIdx.x, wid = tid >> 6, lane = tid & 63;
  const int m = lane & 15, quad = lane >> 4;
  const int row0 = blockIdx.x * 64;
  const int wm = (wid >> 1) * 32, wn = (wid & 1) * 192;
  float4v acc[2][12] = {};
  for (int kc = 0; kc < 512; kc += 64) {
#pragma unroll
    for (int u = 0; u < 4; ++u) {  // A: region = 4 rows x 16 sq (1KB)
      const int r0 = (wid * 4 + u) * 4;
      const int row = r0 + (lane >> 4);
      const int sqg = (lane & 15) ^ (row & 15);
      gll16(x + (size_t)(row0 + row) * 512 + kc + sqg * 4, As + r0 * 256);
    }
#pragma unroll
    for (int u = 0; u < 12; ++u) {  // B: region = 8 rows x 8 oct (1KB)
      const int r0 = (wid * 12 + u) * 8;
      const int row = r0 + (lane >> 3);
      const int og = (lane & 7) ^ (row & 7);
      gll16(wAll + (size_t)row * 512 + kc + og * 8, Bs + r0 * 128);
    }
    __syncthreads();
#pragma unroll
    for (int kk = 0; kk < 64; kk += 32) {
      short8 af[2];
#pragma unroll
      for (int i = 0; i < 2; ++i) {
        const int row = wm + i * 16 + m;
        const int sq0 = (kk >> 2) + quad * 2;
        float4v lo = *(const float4v*)(As + row * 256 + ((sq0 ^ m) * 16));
        float4v hi = *(const float4v*)(As + row * 256 + (((sq0 + 1) ^ m) * 16));
        short8 a;
        a[0] = __builtin_bit_cast(short, __float2bfloat16(lo[0]));
        a[1] = __builtin_bit_cast(short, __float2bfloat16(lo[1]));
        a[2] = __builtin_bit_cast(short, __float2bfloat16(lo[2]));
        a[3] = __builtin_bit_cast(short, __float2bfloat16(lo[3]));
        a[4] = __builtin_bit_cast(short, __float2bfloat16(hi[0]));
        a[5] = __builtin_bit_cast(short, __float2bfloat16(hi[1]));
        a[6] = __builtin_bit_cast(short, __float2bfloat16(hi[2]));
        a[7] = __builtin_bit_cast(short, __float2bfloat16(hi[3]));
        af[i] = a;
      }
      const int oct = (kk >> 3) + quad;
#pragma unroll
      for (int j = 0; j < 12; ++j) {
        short8 bf = *fragp(Bs, wn + j * 16 + m, oct);
#pragma unroll
        for (int i = 0; i < 2; ++i) acc[i][j] = mfma16(af[i], bf, acc[i][j]);
      }
    }
    __syncthreads();
  }
#pragma unroll
  for (int i = 0; i < 2; ++i)
#pragma unroll
    for (int j = 0; j < 12; ++j)
#pragma unroll
      for (int r = 0; r < 4; ++r)
        pgf[(size_t)(row0 + wm + i * 16 + quad * 4 + r) * 384 + wn + j * 16 + m] =
            __float2bfloat16(acc[i][j][r]);
}

// phi_p[b][p][c] = max 2x2 of pgf[b,h,w,64+c]
__global__ __launch_bounds__(256) void k_pool_phi(const __hip_bfloat16* __restrict__ pg,
                                                  __hip_bfloat16* __restrict__ phi_p) {
  int idx = blockIdx.x * 256 + threadIdx.x;  // 524288
  int c = idx & 63;
  int p = (idx >> 6) & 1023;
  int b = idx >> 16;
  int ph = p >> 5, pw = p & 31;
  size_t base = ((size_t)b * 4096 + ph * 128 + pw * 2) * kNP + 64 + c;
  float v0 = __bfloat162float(pg[base]);
  float v1 = __bfloat162float(pg[base + kNP]);
  float v2 = __bfloat162float(pg[base + kNP * 64]);
  float v3 = __bfloat162float(pg[base + kNP * 64 + kNP]);
  phi_p[idx] = __float2bfloat16(fmaxf(fmaxf(v0, v1), fmaxf(v2, v3)));
}

// gT[b][v][p] = max 2x2 of pgf[b,h,w,128+v]
__global__ __launch_bounds__(256) void k_pool_gT(const __hip_bfloat16* __restrict__ pg,
                                                 __hip_bfloat16* __restrict__ gT) {
  __shared__ __hip_bfloat16 t[64][65];
  const int p0 = blockIdx.x * 64, v0 = blockIdx.y * 64, b = blockIdx.z;
#pragma unroll
  for (int it = 0; it < 16; ++it) {
    int li = it * 256 + threadIdx.x;
    int pp = li >> 6, v = li & 63;
    int p = p0 + pp;
    int ph = p >> 5, pw = p & 31;
    size_t base = ((size_t)b * 4096 + ph * 128 + pw * 2) * kNP + 128 + v0 + v;
    float mv = fmaxf(
        fmaxf(__bfloat162float(pg[base]), __bfloat162float(pg[base + kNP])),
        fmaxf(__bfloat162float(pg[base + kNP * 64]), __bfloat162float(pg[base + kNP * 64 + kNP])));
    t[pp][v] = __float2bfloat16(mv);
  }
  __syncthreads();
#pragma unroll
  for (int it = 0; it < 16; ++it) {
    int li = it * 256 + threadIdx.x;
    int v = li >> 6, p = li & 63;
    gT[((size_t)b * 256 + v0 + v) * 1024 + p0 + p] = t[p][v];
  }
}

// ---- fused attention, register-flash: 1 wave/block, 32q x 128v, zero LDS ----
// Chunks of 64 keys. Swapped QK^T: sct[qt][kt][r] = S^T[key][q=q0+qt*16+m]
// (q lane-local). Online softmax per q via 2 cross-quad shfl_xor. P bf16-packed
// and marshaled across quads (xor16 + xor32, index-verified) into PV A-frags.
// K/Q/G all direct 16B/lane global loads (L2-resident, XCD-pinned by b=bid&7).
__global__ __launch_bounds__(64, 2) void k_fattn(
    const __hip_bfloat16* __restrict__ pgf,   // [B*4096][384], theta cols 0..63
    const __hip_bfloat16* __restrict__ phip,  // [B][1024][64]
    const __hip_bfloat16* __restrict__ gT,    // [B][256][1024]
    __hip_bfloat16* __restrict__ O) {         // [B][4096][256]
  const int lane = threadIdx.x;
  const int m = lane & 15, quad = lane >> 4;
  const int bid = blockIdx.x;
  const int b = bid & 7;            // batch -> XCD (round-robin assignment)
  const int rest = bid >> 3;        // 0..255
  const int q0 = (rest & 127) * 32; // 128 q-tiles of 32
  const int vg = rest >> 7;         // v half: vg*128

  const __hip_bfloat16* qbase = pgf + (size_t)(b * kHW + q0) * kNP;
  const __hip_bfloat16* kbase = phip + (size_t)b * kP * 64;
  const __hip_bfloat16* gbase = gT + ((size_t)b * kCV + vg * 128) * kP;

  // Q B-frags: lane holds Q[q0+qt*16+m][chh*32+quad*8 .. +8]
  short8 qf[2][2];
#pragma unroll
  for (int qt = 0; qt < 2; ++qt)
#pragma unroll
    for (int chh = 0; chh < 2; ++chh)
      qf[qt][chh] =
          *(const short8*)(qbase + (size_t)(qt * 16 + m) * kNP + chh * 32 + quad * 8);

  float4v oc[2][8] = {};            // [qt][vt]: rows q=quad*4+r, cols v=vt*16+m
  float mrun[2] = {-3e38f, -3e38f};
  float lrun[2] = {0.f, 0.f};

  // K A-frags for chunk 0: lane holds K[key=kt*16+m][chh*32+quad*8 .. +8]
  short8 kf[4][2];
#pragma unroll
  for (int kt = 0; kt < 4; ++kt)
#pragma unroll
    for (int chh = 0; chh < 2; ++chh)
      kf[kt][chh] =
          *(const short8*)(kbase + (size_t)(kt * 16 + m) * 64 + chh * 32 + quad * 8);

  for (int c = 0; c < 16; ++c) {
    // G half t=0: B-frag lane holds G[p=c*64+quad*8+j][v=vt*16+m] (from gT[v][p])
    short8 g0[8];
#pragma unroll
    for (int vt = 0; vt < 8; ++vt)
      g0[vt] = *(const short8*)(gbase + (size_t)(vt * 16 + m) * kP + c * 64 + quad * 8);

    // QK^T swapped: D[key][q]
    float4v sct[2][4] = {};
#pragma unroll
    for (int kt = 0; kt < 4; ++kt)
#pragma unroll
      for (int chh = 0; chh < 2; ++chh)
#pragma unroll
        for (int qt = 0; qt < 2; ++qt)
          sct[qt][kt] = mfma16(kf[kt][chh], qf[qt][chh], sct[qt][kt]);

    // prefetch next chunk's K (kf dead after QK above)
    if (c < 15) {
#pragma unroll
      for (int kt = 0; kt < 4; ++kt)
#pragma unroll
        for (int chh = 0; chh < 2; ++chh)
          kf[kt][chh] = *(const short8*)(kbase +
              (size_t)((c + 1) * 64 + kt * 16 + m) * 64 + chh * 32 + quad * 8);
    }
    // G half t=1
    short8 g1[8];
#pragma unroll
    for (int vt = 0; vt < 8; ++vt)
      g1[vt] =
          *(const short8*)(gbase + (size_t)(vt * 16 + m) * kP + c * 64 + 32 + quad * 8);

#pragma unroll
    for (int qt = 0; qt < 2; ++qt) {
      // ---- online softmax for q = q0 + qt*16 + m ----
      float cmax = sct[qt][0][0];
#pragma unroll
      for (int kt = 0; kt < 4; ++kt)
#pragma unroll
        for (int r = 0; r < 4; ++r) cmax = fmaxf(cmax, sct[qt][kt][r]);
      cmax = fmaxf(cmax, __shfl_xor(cmax, 16));
      cmax = fmaxf(cmax, __shfl_xor(cmax, 32));
      const float mnew = fmaxf(mrun[qt], cmax);
      const float corr = __expf(mrun[qt] - mnew);
      mrun[qt] = mnew;
      float psum = 0.f;
#pragma unroll
      for (int kt = 0; kt < 4; ++kt)
#pragma unroll
        for (int r = 0; r < 4; ++r) {
          const float e = __expf(sct[qt][kt][r] - mnew);
          sct[qt][kt][r] = e;  // sct now holds P (unnormalized)
          psum += e;
        }
      psum += __shfl_xor(psum, 16);
      psum += __shfl_xor(psum, 32);
      lrun[qt] = lrun[qt] * corr + psum;
      // rescale oc rows: row q = quad*4+r needs corr of lane m = quad*4+r
      float corr_r[4];
#pragma unroll
      for (int r = 0; r < 4; ++r) corr_r[r] = __shfl(corr, quad * 4 + r, 16);
#pragma unroll
      for (int vt = 0; vt < 8; ++vt)
#pragma unroll
        for (int r = 0; r < 4; ++r) oc[qt][vt][r] *= corr_r[r];

      // ---- marshal P into PV A-frags (per 32-p tile) + PV MFMAs ----
#pragma unroll
      for (int t = 0; t < 2; ++t) {
        // own packed pairs: X = kt=2t, Y = kt=2t+1 (d0 = r0|r1<<16, d1 = r2|r3<<16)
        const uint32_t X0 = packbf(sct[qt][2 * t][0], sct[qt][2 * t][1]);
        const uint32_t X1 = packbf(sct[qt][2 * t][2], sct[qt][2 * t][3]);
        const uint32_t Y0 = packbf(sct[qt][2 * t + 1][0], sct[qt][2 * t + 1][1]);
        const uint32_t Y1 = packbf(sct[qt][2 * t + 1][2], sct[qt][2 * t + 1][3]);
        // quad-pair exchange (xor16), normalize to [even-quad, odd-quad] of pair
        const uint32_t X0p = sx16(X0), X1p = sx16(X1), Y0p = sx16(Y0), Y1p = sx16(Y1);
        const bool odd = (quad & 1) != 0;
        const uint32_t Xe0 = odd ? X0p : X0, Xe1 = odd ? X1p : X1;
        const uint32_t Xo0 = odd ? X0 : X0p, Xo1 = odd ? X1 : X1p;
        const uint32_t Ye0 = odd ? Y0p : Y0, Ye1 = odd ? Y1p : Y1;
        const uint32_t Yo0 = odd ? Y0 : Y0p, Yo1 = odd ? Y1 : Y1p;
        // cross-half exchange (xor32)
        const uint32_t Xe0h = sx32(Xe0), Xe1h = sx32(Xe1);
        const uint32_t Xo0h = sx32(Xo0), Xo1h = sx32(Xo1);
        const uint32_t Ye0h = sx32(Ye0), Ye1h = sx32(Ye1);
        const uint32_t Yo0h = sx32(Yo0), Yo1h = sx32(Yo1);
        // select per target quad (verified: q0->[s0,s1]X, q1->xor32 X, q2->xor32 Y, q3->own Y)
        uint4v dv;
        dv[0] = quad == 0 ? Xe0 : quad == 1 ? Xe0h : quad == 2 ? Ye0h : Ye0;
        dv[1] = quad == 0 ? Xe1 : quad == 1 ? Xe1h : quad == 2 ? Ye1h : Ye1;
        dv[2] = quad == 0 ? Xo0 : quad == 1 ? Xo0h : quad == 2 ? Yo0h : Yo0;
        dv[3] = quad == 0 ? Xo1 : quad == 1 ? Xo1h : quad == 2 ? Yo1h : Yo1;
        const short8 af = __builtin_bit_cast(short8, dv);
#pragma unroll
        for (int vt = 0; vt < 8; ++vt)
          oc[qt][vt] = mfma16(af, (t == 0 ? g0[vt] : g1[vt]), oc[qt][vt]);
      }
    }
  }

  // ---- epilogue: scale by 1/l and write O ----
#pragma unroll
  for (int qt = 0; qt < 2; ++qt) {
    const float inv = 1.f / lrun[qt];
    float inv_r[4];
#pragma unroll
    for (int r = 0; r < 4; ++r) inv_r[r] = __shfl(inv, quad * 4 + r, 16);
#pragma unroll
    for (int vt = 0; vt < 8; ++vt)
#pragma unroll
      for (int r = 0; r < 4; ++r) {
        const int row = q0 + qt * 16 + quad * 4 + r;
        O[((size_t)b * kHW + row) * kCV + vg * 128 + vt * 16 + m] =
            __float2bfloat16(oc[qt][vt][r] * inv_r[r]);
      }
  }
}

// ---- out = x + gamma * (O @ w_o), tile 128x128, dbuf, swizzled ----
__global__ __launch_bounds__(256) void k_out(const __hip_bfloat16* __restrict__ A,
                                             const __hip_bfloat16* __restrict__ Bw,
                                             const float* __restrict__ x,
                                             const float* __restrict__ gamma,
                                             float* __restrict__ out) {
  __shared__ __align__(16) char smem[4 * 16384];  // As[2] then Bs[2]
  const int tid = threadIdx.x, wid = tid >> 6, lane = tid & 63;
  const int m = lane & 15, quad = lane >> 4;
  const int row0 = blockIdx.x * 128, col0 = blockIdx.y * 128;
  const int wm = (wid >> 1) * 64, wn = (wid & 1) * 64;
  float4v acc[4][4] = {};
  auto stage = [&](int t, int buf) {
    const int kc = t * 64;
#pragma unroll
    for (int u = 0; u < 4; ++u) {
      const int r0 = (wid * 4 + u) * 8;
      const int row = r0 + (lane >> 3);
      const int og = (lane & 7) ^ (row & 7);
      gll16(A + (size_t)(row0 + row) * 256 + kc + og * 8, smem + buf * 16384 + r0 * 128);
      gll16(Bw + (size_t)(col0 + row) * 256 + kc + og * 8,
            smem + 32768 + buf * 16384 + r0 * 128);
    }
  };
  stage(0, 0);
  __syncthreads();
#pragma unroll
  for (int t = 0; t < 4; ++t) {
    if (t < 3) stage(t + 1, (t + 1) & 1);
    const char* Ab = smem + (t & 1) * 16384;
    const char* Bb = smem + 32768 + (t & 1) * 16384;
    __builtin_amdgcn_s_setprio(1);
#pragma unroll
    for (int kk = 0; kk < 64; kk += 32) {
      const int oct = (kk >> 3) + quad;
      short8 af[4], bf[4];
#pragma unroll
      for (int i = 0; i < 4; ++i) af[i] = *fragp(Ab, wm + i * 16 + m, oct);
#pragma unroll
      for (int j = 0; j < 4; ++j) bf[j] = *fragp(Bb, wn + j * 16 + m, oct);
#pragma unroll
      for (int i = 0; i < 4; ++i)
#pragma unroll
        for (int j = 0; j < 4; ++j) acc[i][j] = mfma16(af[i], bf[j], acc[i][j]);
    }
    __builtin_amdgcn_s_setprio(0);
    __syncthreads();
  }
  const float g = gamma[0];
#pragma unroll
  for (int i = 0; i < 4; ++i)
#pragma unroll
    for (int j = 0; j < 4; ++j) {
      const int cc = col0 + wn + j * 16 + m;
      const int rb = row0 + wm + i * 16 + quad * 4;
#pragma unroll
      for (int r = 0; r < 4; ++r) {
        const size_t idx = (size_t)(rb + r) * 512 + cc;
        out[idx] = x[idx] + g * acc[i][j][r];
      }
    }
}

extern "C" void kernel_launch(void* const* d_in, const int* in_sizes, int n_in,
                              void* d_out, int out_size, void* d_ws, size_t ws_size,
                              hipStream_t stream) {
  (void)in_sizes; (void)n_in; (void)out_size; (void)ws_size;
  const float* x     = (const float*)d_in[0];
  const float* wt    = (const float*)d_in[1];
  const float* wphi  = (const float*)d_in[2];
  const float* wg    = (const float*)d_in[3];
  const float* wo    = (const float*)d_in[4];
  const float* gamma = (const float*)d_in[5];
  float* out = (float*)d_out;

  char* ws = (char*)d_ws;
  __hip_bfloat16* wAll = (__hip_bfloat16*)(ws);              //    393,216
  __hip_bfloat16* woT  = (__hip_bfloat16*)(ws + 393216);     //    262,144
  __hip_bfloat16* pgf  = (__hip_bfloat16*)(ws + 655360);     // 25,165,824
  __hip_bfloat16* phip = (__hip_bfloat16*)(ws + 25821184);   //  1,048,576
  __hip_bfloat16* gT   = (__hip_bfloat16*)(ws + 26869760);   //  4,194,304
  __hip_bfloat16* O    = (__hip_bfloat16*)(ws + 31064064);   // 16,777,216  (total 47.8MB)

  k_pack_w<<<1280, 256, 0, stream>>>(wt, wphi, wg, wo, wAll, woT);
  k_proj<<<512, 256, 0, stream>>>(x, wAll, pgf);
  k_pool_phi<<<2048, 256, 0, stream>>>(pgf, phip);
  k_pool_gT<<<dim3(16, 4, 8), 256, 0, stream>>>(pgf, gT);
  k_fattn<<<dim3(2048), 64, 0, stream>>>(pgf, phip, gT, O);
  k_out<<<dim3(256, 4), 256, 0, stream>>>(O, woT, x, gamma, out);
}